// Round 3
// baseline (153.104 us; speedup 1.0000x reference)
//
#include <hip/hip_runtime.h>
#include <stdint.h>

// S=512, B=64, H=8, K=12, P=9, L=137, T=4096, THRESH=4
// Workspace layout (u32 units):
//   WS_TABLE [0, 65536)        packed ram tables: 128 u32 per hb      = 256 KB
//   WS_AK    [65536, 196608)   Ak partial addrs: 512 u16 per hb       = 512 KB
//   WS_AQ    [196608, 327680)  Aq partial addrs: 512 u16 per hb       = 512 KB
//   WS_PAR   [327680, 335872)  parity bits: [hb][chunk(8)][2] u32     = 32 KB
#define WS_TABLE 0
#define WS_AK    65536
#define WS_AQ    196608
#define WS_PAR   327680

// ---- Kernel 0: pack ram bit-tables + precompute Aq/Ak address arrays ----
__global__ __launch_bounds__(256) void softram_pack_kernel(
    const int* __restrict__ tokens,   // (512, 64)
    const int* __restrict__ conn,     // (8, 64, 12)
    const float* __restrict__ ram,    // (8, 64, 4096) values in {0,1}
    uint32_t* __restrict__ ws)
{
    const int tid = threadIdx.x, lane = tid & 63, w = tid >> 6;
    if (blockIdx.x < 512) {
        const int hb = blockIdx.x;
        const float* ramp = ram + (size_t)hb * 4096;
        uint32_t* tp = ws + WS_TABLE + hb * 128;
        #pragma unroll
        for (int c = 0; c < 16; ++c) {
            float v = ramp[c * 256 + tid];
            unsigned long long m = __ballot(v > 0.5f);
            if (lane == 0) {
                tp[c * 8 + w * 2]     = (uint32_t)m;
                tp[c * 8 + w * 2 + 1] = (uint32_t)(m >> 32);
            }
        }
    } else {
        const int hb = blockIdx.x - 512;
        const int* cp = conn + hb * 12;          // uniform -> scalar loads
        int ck[12];
        #pragma unroll
        for (int k = 0; k < 12; ++k) ck[k] = cp[k];
        unsigned short* akg = (unsigned short*)(ws + WS_AK) + hb * 512;
        unsigned short* aqg = (unsigned short*)(ws + WS_AQ) + hb * 512;
        #pragma unroll
        for (int rep = 0; rep < 2; ++rep) {
            int s = tid + rep * 256;
            int aq = 0, ak = 0;
            #pragma unroll
            for (int k = 0; k < 12; ++k) {
                int c = ck[k];                    // wave-uniform branch
                if (c < 64)       aq |= tokens[s * 64 + c] << k;
                else if (c < 128) ak |= tokens[s * 64 + (c - 64)] << k;
            }
            aqg[s] = (unsigned short)aq;
            akg[s] = (unsigned short)ak;
        }
    }
}

// ---- chunk parity, NR r-bits specialized (r-contribution in VALU) ----
template<int NR>
__device__ __noinline__ uint32_t chunk_parity(
    int c, int w, int lane, int aq,
    const unsigned short* AkL, const uint32_t* tbl,
    int p0, int k0, int p1, int k1)
{
    uint32_t acc = 0;
    for (int sb = w; sb <= c; sb += 4) {
        int akv = (int)AkL[sb * 64 + lane];
        int dbase = (c - sb) * 64 + lane;        // d = dbase - jj
        if (sb < c) {                            // full sub-block, d >= 1
            #pragma unroll
            for (int jj = 0; jj < 64; ++jj) {
                int sak = __builtin_amdgcn_readlane(akv, jj);
                int d = dbase - jj;
                int addr = aq + sak;
                if (NR > 0) addr += ((d >> p0) & 1) << k0;
                if (NR > 1) addr += ((d >> p1) & 1) << k1;
                acc ^= tbl[addr >> 5] >> (addr & 31);   // parity in bit 0
            }
        } else {                                 // tail: active iff jj <= lane
            #pragma unroll
            for (int jj = 0; jj < 64; ++jj) {
                int sak = __builtin_amdgcn_readlane(akv, jj);
                int d = lane - jj;
                int dm = d < 0 ? 0 : d;
                int addr = aq + sak;
                if (NR > 0) addr += ((dm >> p0) & 1) << k0;
                if (NR > 1) addr += ((dm >> p1) & 1) << k1;
                uint32_t bit = tbl[addr >> 5] >> (addr & 31);
                acc ^= (d >= 0) ? bit : 0u;
            }
        }
    }
    return acc;
}

// generic fallback for nr >= 3 (~3.5% of blocks)
__device__ __noinline__ uint32_t chunk_parity_gen(
    int c, int w, int lane, int aq,
    const unsigned short* AkL, const uint32_t* tbl,
    int nr, const int* rp, const int* rk)
{
    uint32_t acc = 0;
    for (int sb = w; sb <= c; sb += 4) {
        int akv = (int)AkL[sb * 64 + lane];
        int dbase = (c - sb) * 64 + lane;
        bool tail = (sb == c);
        #pragma unroll 8
        for (int jj = 0; jj < 64; ++jj) {
            int sak = __builtin_amdgcn_readlane(akv, jj);
            int d = dbase - jj;
            int dm = d < 0 ? 0 : d;
            int addr = aq + sak;
            for (int t = 0; t < nr; ++t) addr += ((dm >> rp[t]) & 1) << rk[t];
            uint32_t bit = tbl[addr >> 5] >> (addr & 31);
            acc ^= (!tail || d >= 0) ? bit : 0u;     // full blocks: d>=1 anyway
        }
    }
    return acc;
}

// ---- Kernel 1: parity. 4 blocks per hb (block q owns chunks {q, 7-q});
//      each chunk's sub-blocks split mod 4 across the 4 waves. ----
__global__ __launch_bounds__(256) void softram_parity_kernel(
    const int* __restrict__ conn, uint32_t* __restrict__ ws)
{
    __shared__ uint32_t tbl[128];                // 4096-bit table
    __shared__ unsigned short AkL[512];          // Ak for readlane staging
    __shared__ unsigned long long parbuf[2][4];

    const int tid  = threadIdx.x;
    const int lane = tid & 63;
    const int w    = tid >> 6;
    const int hb   = blockIdx.x >> 2;
    const int q    = blockIdx.x & 3;

    if (tid < 128) tbl[tid] = ws[WS_TABLE + hb * 128 + tid];
    ((uint32_t*)AkL)[tid] = ws[WS_AK + hb * 256 + tid];
    __syncthreads();

    // wave-uniform r-bit list from conn
    const int* cp = conn + hb * 12;
    int nr = 0, rp[12], rk[12];
    #pragma unroll
    for (int k = 0; k < 12; ++k) {
        int cv = cp[k];
        if (cv >= 128) { rp[nr] = cv - 128; rk[nr] = k; ++nr; }
    }

    const unsigned short* aqg = (const unsigned short*)(ws + WS_AQ) + hb * 512;
    const int chunks[2] = { q, 7 - q };
    uint32_t accs[2];

    for (int ci = 0; ci < 2; ++ci) {
        const int c  = chunks[ci];
        const int aq = (int)aqg[c * 64 + lane];
        uint32_t a;
        switch (nr) {
            case 0:  a = chunk_parity<0>(c, w, lane, aq, AkL, tbl, 0, 0, 0, 0); break;
            case 1:  a = chunk_parity<1>(c, w, lane, aq, AkL, tbl, rp[0], rk[0], 0, 0); break;
            case 2:  a = chunk_parity<2>(c, w, lane, aq, AkL, tbl, rp[0], rk[0], rp[1], rk[1]); break;
            default: a = chunk_parity_gen(c, w, lane, aq, AkL, tbl, nr, rp, rk); break;
        }
        accs[ci] = a & 1u;
    }

    #pragma unroll
    for (int ci = 0; ci < 2; ++ci) {
        unsigned long long m = __ballot(accs[ci] != 0);
        if (lane == 0) parbuf[ci][w] = m;
    }
    __syncthreads();

    if (tid == 0) {
        uint32_t* wp = ws + WS_PAR;
        #pragma unroll
        for (int ci = 0; ci < 2; ++ci) {
            int c = chunks[ci];
            unsigned long long m = parbuf[ci][0] ^ parbuf[ci][1]
                                 ^ parbuf[ci][2] ^ parbuf[ci][3];
            wp[(hb * 8 + c) * 2]     = (uint32_t)m;
            wp[(hb * 8 + c) * 2 + 1] = (uint32_t)(m >> 32);
        }
    }
}

// ---- Kernel 2: majority vote over heads ----
__global__ __launch_bounds__(256) void softram_vote_kernel(
    const uint32_t* __restrict__ ws, float* __restrict__ out)
{
    int t = blockIdx.x * 256 + threadIdx.x;      // t = i*64 + b
    int b = t & 63;
    int i = t >> 6;
    const uint32_t* wp = ws + WS_PAR;
    int sum = 0;
    #pragma unroll
    for (int h = 0; h < 8; ++h) {
        int hb = h * 64 + b;
        uint32_t wv = wp[(hb * 8 + (i >> 6)) * 2 + ((i >> 5) & 1)];
        sum += (wv >> (i & 31)) & 1u;
    }
    out[t] = (sum > 4) ? 1.0f : 0.0f;            // THRESH = H/2 = 4
}

extern "C" void kernel_launch(void* const* d_in, const int* in_sizes, int n_in,
                              void* d_out, int out_size, void* d_ws, size_t ws_size,
                              hipStream_t stream) {
    const int*   tokens = (const int*)d_in[0];   // (512, 64)
    const int*   conn   = (const int*)d_in[1];   // (8, 64, 12)
    const float* ram    = (const float*)d_in[2]; // (8, 64, 4096)
    float*       out    = (float*)d_out;         // (512, 64)
    uint32_t*    ws     = (uint32_t*)d_ws;       // ~1.3 MB used

    softram_pack_kernel<<<1024, 256, 0, stream>>>(tokens, conn, ram, ws);
    softram_parity_kernel<<<2048, 256, 0, stream>>>(conn, ws);
    softram_vote_kernel<<<128, 256, 0, stream>>>(ws, out);
}

// Round 4
// 119.125 us; speedup vs baseline: 1.2852x; 1.2852x over previous
//
#include <hip/hip_runtime.h>
#include <stdint.h>

// S=512, B=64, H=8, K=12, P=9, L=137, T=4096, THRESH=4
// Workspace layout (u32 units):
//   WS_TABLE [0, 65536)        packed ram tables: 128 u32 per hb      = 256 KB
//   WS_AK    [65536, 196608)   Ak partial addrs: 512 u16 per hb       = 512 KB
//   WS_AQ    [196608, 327680)  Aq partial addrs: 512 u16 per hb       = 512 KB
//   WS_PAR   [327680, 335872)  parity bits: [hb][chunk(8)][2] u32     = 32 KB
#define WS_TABLE 0
#define WS_AK    65536
#define WS_AQ    196608
#define WS_PAR   327680

// ---- Kernel 0: pack ram bit-tables + precompute Aq/Ak address arrays ----
__global__ __launch_bounds__(256) void softram_pack_kernel(
    const int* __restrict__ tokens,   // (512, 64)
    const int* __restrict__ conn,     // (8, 64, 12)
    const float* __restrict__ ram,    // (8, 64, 4096) values in {0,1}
    uint32_t* __restrict__ ws)
{
    const int tid = threadIdx.x, lane = tid & 63, w = tid >> 6;
    if (blockIdx.x < 512) {
        const int hb = blockIdx.x;
        const float* ramp = ram + (size_t)hb * 4096;
        uint32_t* tp = ws + WS_TABLE + hb * 128;
        #pragma unroll
        for (int c = 0; c < 16; ++c) {
            float v = ramp[c * 256 + tid];
            unsigned long long m = __ballot(v > 0.5f);
            if (lane == 0) {
                tp[c * 8 + w * 2]     = (uint32_t)m;
                tp[c * 8 + w * 2 + 1] = (uint32_t)(m >> 32);
            }
        }
    } else {
        const int hb = blockIdx.x - 512;
        const int* cp = conn + hb * 12;          // uniform -> scalar loads
        int ck[12];
        #pragma unroll
        for (int k = 0; k < 12; ++k) ck[k] = cp[k];
        unsigned short* akg = (unsigned short*)(ws + WS_AK) + hb * 512;
        unsigned short* aqg = (unsigned short*)(ws + WS_AQ) + hb * 512;
        #pragma unroll
        for (int rep = 0; rep < 2; ++rep) {
            int s = tid + rep * 256;
            int aq = 0, ak = 0;
            #pragma unroll
            for (int k = 0; k < 12; ++k) {
                int c = ck[k];                    // wave-uniform branch
                if (c < 64)       aq |= tokens[s * 64 + c] << k;
                else if (c < 128) ak |= tokens[s * 64 + (c - 64)] << k;
            }
            aqg[s] = (unsigned short)aq;
            akg[s] = (unsigned short)ak;
        }
    }
}

// ---- Kernel 1: parity. 4 blocks per hb (block q owns chunks {q, 7-q});
//      each chunk's sub-blocks split mod 4 across the 4 waves.
//      Everything inlined: table reads MUST stay ds_read (no flat loads). ----
__global__ __launch_bounds__(256) void softram_parity_kernel(
    const int* __restrict__ conn, uint32_t* __restrict__ ws)
{
    __shared__ uint32_t tbl[128];                // 4096-bit table
    __shared__ unsigned short AkL[512];          // Ak staged for readlane
    __shared__ unsigned short ArL[512];          // Ar (generic path only)
    __shared__ unsigned long long parbuf[2][4];

    const int tid  = threadIdx.x;
    const int lane = tid & 63;
    const int w    = tid >> 6;
    const int hb   = blockIdx.x >> 2;
    const int q    = blockIdx.x & 3;

    if (tid < 128) tbl[tid] = ws[WS_TABLE + hb * 128 + tid];
    ((uint32_t*)AkL)[tid] = ws[WS_AK + hb * 256 + tid];

    // wave-uniform r-bit info from conn (no local arrays -> no scratch)
    const int* cp = conn + hb * 12;
    int ck[12];
    #pragma unroll
    for (int k = 0; k < 12; ++k) ck[k] = cp[k];
    int p0 = 0, m0 = 0, p1 = 0, m1 = 0, nr = 0;
    #pragma unroll
    for (int k = 0; k < 12; ++k) {
        int cv = ck[k];
        if (cv >= 128) {
            if (nr == 0)      { p0 = cv - 128; m0 = 1 << k; }
            else if (nr == 1) { p1 = cv - 128; m1 = 1 << k; }
            ++nr;
        }
    }

    // ArL for the generic (nr>=3) fallback — cheap, compute always
    #pragma unroll
    for (int rep = 0; rep < 2; ++rep) {
        int s = tid + rep * 256;
        int ar = 0;
        #pragma unroll
        for (int k = 0; k < 12; ++k) {
            int cv = ck[k];
            if (cv >= 128) ar += ((s >> (cv - 128)) & 1) << k;
        }
        ArL[s] = (unsigned short)ar;
    }
    __syncthreads();

    const unsigned short* aqg = (const unsigned short*)(ws + WS_AQ) + hb * 512;
    const int chunks[2] = { q, 7 - q };
    uint32_t accs[2];

    for (int ci = 0; ci < 2; ++ci) {
        const int c  = chunks[ci];
        const int aq = (int)aqg[c * 64 + lane];
        uint32_t acc = 0;
        if (nr <= 2) {                           // 96% of hb: r-part in VALU
            for (int sb = w; sb < c; sb += 4) {  // full sub-blocks, d >= 1
                int akv = (int)AkL[sb * 64 + lane];
                int dbase = (c - sb) * 64 + lane;
                #pragma unroll
                for (int jj = 0; jj < 64; ++jj) {
                    int sak = __builtin_amdgcn_readlane(akv, jj);
                    int d = dbase - jj;
                    int addr = aq + sak + ((d >> p0) & 1) * m0
                                        + ((d >> p1) & 1) * m1;
                    acc ^= tbl[addr >> 5] >> (addr & 31);   // parity in bit 0
                }
            }
            if (w == (c & 3)) {                  // tail sub-block sb == c
                int akv = (int)AkL[c * 64 + lane];
                #pragma unroll
                for (int jj = 0; jj < 64; ++jj) {
                    int sak = __builtin_amdgcn_readlane(akv, jj);
                    int d = lane - jj;           // may be < 0
                    int addr = aq + sak + ((d >> p0) & 1) * m0
                                        + ((d >> p1) & 1) * m1;
                    uint32_t keep = ~(uint32_t)(d >> 31);   // 0 if d<0
                    acc ^= (tbl[addr >> 5] >> (addr & 31)) & keep;
                }
            }
        } else {                                 // rare: Ar via LDS
            for (int sb = w; sb <= c; sb += 4) {
                int akv = (int)AkL[sb * 64 + lane];
                int dbase = (c - sb) * 64 + lane;
                #pragma unroll 8
                for (int jj = 0; jj < 64; ++jj) {
                    int sak = __builtin_amdgcn_readlane(akv, jj);
                    int d = dbase - jj;
                    int dm = d < 0 ? 0 : d;
                    int addr = aq + sak + (int)ArL[dm];
                    uint32_t keep = ~(uint32_t)(d >> 31);
                    acc ^= (tbl[addr >> 5] >> (addr & 31)) & keep;
                }
            }
        }
        accs[ci] = acc & 1u;
    }

    #pragma unroll
    for (int ci = 0; ci < 2; ++ci) {
        unsigned long long m = __ballot(accs[ci] != 0);
        if (lane == 0) parbuf[ci][w] = m;
    }
    __syncthreads();

    if (tid == 0) {
        uint32_t* wp = ws + WS_PAR;
        #pragma unroll
        for (int ci = 0; ci < 2; ++ci) {
            int c = chunks[ci];
            unsigned long long m = parbuf[ci][0] ^ parbuf[ci][1]
                                 ^ parbuf[ci][2] ^ parbuf[ci][3];
            wp[(hb * 8 + c) * 2]     = (uint32_t)m;
            wp[(hb * 8 + c) * 2 + 1] = (uint32_t)(m >> 32);
        }
    }
}

// ---- Kernel 2: majority vote over heads ----
__global__ __launch_bounds__(256) void softram_vote_kernel(
    const uint32_t* __restrict__ ws, float* __restrict__ out)
{
    int t = blockIdx.x * 256 + threadIdx.x;      // t = i*64 + b
    int b = t & 63;
    int i = t >> 6;
    const uint32_t* wp = ws + WS_PAR;
    int sum = 0;
    #pragma unroll
    for (int h = 0; h < 8; ++h) {
        int hb = h * 64 + b;
        uint32_t wv = wp[(hb * 8 + (i >> 6)) * 2 + ((i >> 5) & 1)];
        sum += (wv >> (i & 31)) & 1u;
    }
    out[t] = (sum > 4) ? 1.0f : 0.0f;            // THRESH = H/2 = 4
}

extern "C" void kernel_launch(void* const* d_in, const int* in_sizes, int n_in,
                              void* d_out, int out_size, void* d_ws, size_t ws_size,
                              hipStream_t stream) {
    const int*   tokens = (const int*)d_in[0];   // (512, 64)
    const int*   conn   = (const int*)d_in[1];   // (8, 64, 12)
    const float* ram    = (const float*)d_in[2]; // (8, 64, 4096)
    float*       out    = (float*)d_out;         // (512, 64)
    uint32_t*    ws     = (uint32_t*)d_ws;       // ~1.35 MB used

    softram_pack_kernel<<<1024, 256, 0, stream>>>(tokens, conn, ram, ws);
    softram_parity_kernel<<<2048, 256, 0, stream>>>(conn, ws);
    softram_vote_kernel<<<128, 256, 0, stream>>>(ws, out);
}